// Round 10
// baseline (500.396 us; speedup 1.0000x reference)
//
#include <hip/hip_runtime.h>
#include <hip/hip_cooperative_groups.h>
#include <hip/hip_bf16.h>
#include <math.h>

namespace cg = cooperative_groups;

#define NQ 196
#define BATCH 4
#define HD 512            // H * D_K == D_MODEL
#define NH 8
#define DK 64
#define MROWS 784         // BATCH*NQ = 49*16
#define MPAD 832          // bf16 ws arrays row slack (attn tile overhang reads)
#define GRIDB 416         // 13*8*4 == attn items; <= co-residency (2 blk/CU)
#define NTHR 512

typedef __attribute__((ext_vector_type(8))) short short8;
typedef __attribute__((ext_vector_type(4))) short short4v;
typedef __attribute__((ext_vector_type(4))) float float4v;

__device__ __forceinline__ float b2f(short s) {
  return __uint_as_float(((unsigned)(unsigned short)s) << 16);
}
__device__ __forceinline__ short f2b(float x) {
  return __builtin_bit_cast(short, __float2bfloat16(x));
}
__device__ __forceinline__ float fexp2(float x) {
  float r; asm("v_exp_f32 %0, %1" : "=v"(r) : "v"(x)); return r;
}
__device__ __forceinline__ float frcp(float x) {
  float r; asm("v_rcp_f32 %0, %1" : "=v"(r) : "v"(x)); return r;
}
__device__ __forceinline__ void cvt4(float4 v, short4v& hi, short4v& lo) {
  float x[4] = {v.x, v.y, v.z, v.w};
  #pragma unroll
  for (int i = 0; i < 4; ++i) {
    hi[i] = f2b(x[i]);
    lo[i] = f2b(x[i] - b2f(hi[i]));
  }
}
__device__ __forceinline__ void gload_lds16(const void* g, void* l) {
  __builtin_amdgcn_global_load_lds(
      (const __attribute__((address_space(1))) unsigned int*)g,
      (__attribute__((address_space(3))) unsigned int*)l, 16, 0, 0);
}

struct FusedArgs {
  const float *queries, *keys, *values;
  const float *Wq, *bq, *Wk, *bk, *Wv, *bv, *Wo, *bo, *scale;
  float *q_sig, *k_p, *v_p, *image, *outp;
  short *qsh, *qsl, *ksh, *ksl;
  short *Wqh, *Wql, *Wkh, *Wkl, *Wvh, *Wvl, *Woh, *Wol;
};

struct AttnSmem { float S[16][210]; float R[8][16][64]; };
union SmemU { short gemm[20480]; AttnSmem at; };   // 46208 B

// ---------------- phase 0: weight split fp32 -> bf16 hi/lo ----------------
__device__ __forceinline__ void phase0_body(const FusedArgs& a, int bid) {
  const int t = threadIdx.x;
  for (unsigned idx = (unsigned)bid * NTHR + t; idx < 262144u;
       idx += (unsigned)GRIDB * NTHR) {
    const int seg = idx >> 16;                    // 4 x 65536 float4 groups
    const size_t off = (size_t)(idx & 65535u) << 2;
    const float* s; short* hh; short* ll;
    if (seg == 0)      { s = a.Wq; hh = a.Wqh; ll = a.Wql; }
    else if (seg == 1) { s = a.Wk; hh = a.Wkh; ll = a.Wkl; }
    else if (seg == 2) { s = a.Wv; hh = a.Wvh; ll = a.Wvl; }
    else               { s = a.Wo; hh = a.Woh; ll = a.Wol; }
    float4 v = *(const float4*)(s + off);
    short4v h, l; cvt4(v, h, l);
    *(short4v*)(hh + off) = h;
    *(short4v*)(ll + off) = l;
  }
}

// ---------------- GEMM tile: 16(M)x64(N), k-split-2, BK=32 ----------------
// A fp32 (cvt on the fly), B pre-split bf16 via global_load_lds.
__device__ __forceinline__ void gemm_tile(
    const float* __restrict__ X, const short* __restrict__ Wh,
    const short* __restrict__ Wl, const float* __restrict__ bias,
    const float* __restrict__ gate, float* __restrict__ Cf,
    short* __restrict__ Ch, short* __restrict__ Cl,
    int m0, int n0, short* smem) {
  const int K = HD, N = HD;
  short* const A_ = smem;                       // [g*2+buf][hl][16*32] 512 each
  short* const B_ = smem + 4096;                // [g*2+buf][hl][64*32] 2048 each
  float* const redC = (float*)smem;             // 4KB, aliases A after barrier

  const int t = threadIdx.x;
  const int g = t >> 8;
  const int tt = t & 255;
  const int ln = t & 63, lm = ln & 15, quad = ln >> 4;
  const int w = (t >> 6) & 3;
  const int kb = g << 8;

  const int aRow = (tt & 127) >> 3, aK = (tt & 7) << 2;
  const bool aload = tt < 128;
  const float* Ap = X + (size_t)(m0 + aRow) * K + kb + aK;
  const int aIdx = aRow * 32 + aK;
  const int bRow = tt >> 2, bK = (tt & 3) << 3;
  const short* Bph = Wh + (size_t)(n0 + bRow) * K + kb + bK;
  const short* Bpl = Wl + (size_t)(n0 + bRow) * K + kb + bK;

  const int wn = w << 4;
  float4v acc = {0.f, 0.f, 0.f, 0.f};

  const int T = 8;
  float4 ra = aload ? *(const float4*)Ap : make_float4(0.f, 0.f, 0.f, 0.f);
  gload_lds16(Bph, &B_[(((g << 1) + 0) * 2 + 0) * 2048 + tt * 8]);
  gload_lds16(Bpl, &B_[(((g << 1) + 0) * 2 + 1) * 2048 + tt * 8]);
  if (aload) {
    short4v ahi, alo; cvt4(ra, ahi, alo);
    *(short4v*)&A_[(((g << 1) + 0) * 2 + 0) * 512 + aIdx] = ahi;
    *(short4v*)&A_[(((g << 1) + 0) * 2 + 1) * 512 + aIdx] = alo;
  }

  for (int kt = 0; kt < T; ++kt) {
    const int buf = kt & 1;
    __syncthreads();                            // buf ready (DMA drained)
    if (kt + 1 < T) {
      if (aload) ra = *(const float4*)(Ap + (size_t)(kt + 1) * 32);
      const int nb = buf ^ 1;
      gload_lds16(Bph + (size_t)(kt + 1) * 32, &B_[(((g << 1) + nb) * 2 + 0) * 2048 + tt * 8]);
      gload_lds16(Bpl + (size_t)(kt + 1) * 32, &B_[(((g << 1) + nb) * 2 + 1) * 2048 + tt * 8]);
    }
    const short* Ab = &A_[((g << 1) + buf) * 2 * 512];
    const short* Bb = &B_[((g << 1) + buf) * 2 * 2048];
    short8 fah = *(const short8*)&Ab[0 * 512 + lm * 32 + (quad << 3)];
    short8 fal = *(const short8*)&Ab[1 * 512 + lm * 32 + (quad << 3)];
    short8 fbh = *(const short8*)&Bb[0 * 2048 + (wn + lm) * 32 + (quad << 3)];
    short8 fbl = *(const short8*)&Bb[1 * 2048 + (wn + lm) * 32 + (quad << 3)];
    acc = __builtin_amdgcn_mfma_f32_16x16x32_bf16(fah, fbh, acc, 0,0,0);
    acc = __builtin_amdgcn_mfma_f32_16x16x32_bf16(fah, fbl, acc, 0,0,0);
    acc = __builtin_amdgcn_mfma_f32_16x16x32_bf16(fal, fbh, acc, 0,0,0);
    if (kt + 1 < T) {
      const int nb = buf ^ 1;
      if (aload) {
        short4v ahi, alo; cvt4(ra, ahi, alo);
        *(short4v*)&A_[(((g << 1) + nb) * 2 + 0) * 512 + aIdx] = ahi;
        *(short4v*)&A_[(((g << 1) + nb) * 2 + 1) * 512 + aIdx] = alo;
      }
    }
  }

  __syncthreads();
  if (g == 1) *(float4v*)&redC[tt * 4] = acc;
  __syncthreads();
  if (g == 0) {
    const int n = n0 + wn + lm;
    const float bv = bias[n];
    #pragma unroll
    for (int r = 0; r < 4; ++r) {
      const int m = m0 + (quad << 2) + r;
      float c = acc[r] + redC[tt * 4 + r] + bv;
      if (gate) {
        const float qg = gate[(size_t)m * N + n];
        c = __fdividef(c, 1.f + __expf(-qg * c));   // sigmoid(qg*c)*c
      }
      if (Cf) Cf[(size_t)m * N + n] = c;
      if (Ch) {
        const short hi = f2b(c);
        Ch[(size_t)m * N + n] = hi;
        Cl[(size_t)m * N + n] = f2b(c - b2f(hi));
      }
    }
  }
  __syncthreads();   // protect redC/A_ aliasing before next tile's staging
}

// ---------------- phase 1: projections ----------------
__device__ __forceinline__ void proj_body(const FusedArgs& a, int bid, short* smem) {
  for (int tile = bid; tile < 1176; tile += GRIDB) {
    const int z = tile / 392;
    const int r = tile - z * 392;
    const int m0 = (r >> 3) << 4;
    const int n0 = (r & 7) << 6;
    const float* X; const short* Wh; const short* Wl; const float* bias;
    float* Cf; short* Ch; short* Cl;
    if (z == 0)      { X=a.queries; Wh=a.Wqh; Wl=a.Wql; bias=a.bq; Cf=a.q_sig; Ch=a.qsh; Cl=a.qsl; }
    else if (z == 1) { X=a.keys;    Wh=a.Wkh; Wl=a.Wkl; bias=a.bk; Cf=a.k_p;   Ch=a.ksh; Cl=a.ksl; }
    else             { X=a.values;  Wh=a.Wvh; Wl=a.Wvl; bias=a.bv; Cf=a.v_p;   Ch=nullptr; Cl=nullptr; }
    gemm_tile(X, Wh, Wl, bias, nullptr, Cf, Ch, Cl, m0, n0, smem);
  }
}

// ---------------- phase 2: fused scores + softmax + gated PV ----------------
__device__ __forceinline__ void attn_body(const FusedArgs& a, int bid, AttnSmem& sm) {
  const int qt = bid % 13;
  const int h  = (bid / 13) % NH;
  const int b  = bid / (13 * NH);
  const int q0 = qt * 16;
  const int t  = threadIdx.x;
  const int w = t >> 6, ln = t & 63;
  const int lm = ln & 15, quad = ln >> 4;
  const float L2E = 1.4426950408889634f;

  // phase 2a: S = q_sig . k_p^T (bf16x3 MFMA), waves stride nt by 8
  const size_t abase = ((size_t)(b * NQ) + q0 + lm) * HD + h * DK + (quad << 3);
  short8 ah0 = *(const short8*)(a.qsh + abase);
  short8 ah1 = *(const short8*)(a.qsh + abase + 32);
  short8 al0 = *(const short8*)(a.qsl + abase);
  short8 al1 = *(const short8*)(a.qsl + abase + 32);

  for (int nt = w; nt < 13; nt += 8) {
    const size_t bbase = ((size_t)(b * NQ) + nt * 16 + lm) * HD + h * DK + (quad << 3);
    short8 bh0 = *(const short8*)(a.ksh + bbase);
    short8 bh1 = *(const short8*)(a.ksh + bbase + 32);
    short8 bl0 = *(const short8*)(a.ksl + bbase);
    short8 bl1 = *(const short8*)(a.ksl + bbase + 32);
    float4v acc = {0.f, 0.f, 0.f, 0.f};
    acc = __builtin_amdgcn_mfma_f32_16x16x32_bf16(ah0, bh0, acc, 0,0,0);
    acc = __builtin_amdgcn_mfma_f32_16x16x32_bf16(ah1, bh1, acc, 0,0,0);
    acc = __builtin_amdgcn_mfma_f32_16x16x32_bf16(ah0, bl0, acc, 0,0,0);
    acc = __builtin_amdgcn_mfma_f32_16x16x32_bf16(ah1, bl1, acc, 0,0,0);
    acc = __builtin_amdgcn_mfma_f32_16x16x32_bf16(al0, bh0, acc, 0,0,0);
    acc = __builtin_amdgcn_mfma_f32_16x16x32_bf16(al1, bh1, acc, 0,0,0);
    #pragma unroll
    for (int r = 0; r < 4; ++r)
      sm.S[(quad << 2) + r][nt * 16 + lm] = acc[r];
  }
  __syncthreads();

  // phase 2b: softmax in place (wave w: rows 2w, 2w+1)
  for (int i = 0; i < 2; ++i) {
    const int rr = (w << 1) + i;
    const int q = q0 + rr;
    const bool qok = q < NQ;
    const float* srow = a.scale + ((size_t)h * NQ + (qok ? q : 0)) * NQ;
    float att[4];
    #pragma unroll
    for (int j = 0; j < 4; ++j) {
      const int c = ln + (j << 6);
      att[j] = -1e30f;
      if (c < NQ) att[j] = sm.S[rr][c] * srow[c] * L2E;
    }
    float m = fmaxf(fmaxf(att[0], att[1]), fmaxf(att[2], att[3]));
    #pragma unroll
    for (int off = 32; off; off >>= 1) m = fmaxf(m, __shfl_xor(m, off, 64));
    float e[4], s = 0.f;
    #pragma unroll
    for (int j = 0; j < 4; ++j) { e[j] = fexp2(att[j] - m); s += e[j]; }
    #pragma unroll
    for (int off = 32; off; off >>= 1) s += __shfl_xor(s, off, 64);
    const float rinv = __fdividef(1.f, s);
    #pragma unroll
    for (int j = 0; j < 4; ++j) {
      const int c = ln + (j << 6);
      if (c < NQ) sm.S[rr][c] = e[j] * rinv;
    }
  }
  __syncthreads();

  // phase 2c: gated PV. thread = (d = ln, kgroup = w of 8)
  const int d = ln;
  const int kg = w;
  const int kbeg = (kg * 49) >> 1;
  const int kend = ((kg + 1) * 49) >> 1;
  const float LOG2E = 1.4426950408889634f;

  float nqs[16];
  #pragma unroll
  for (int qi = 0; qi < 16; ++qi) {
    const int row = min(b * NQ + q0 + qi, MROWS - 1);
    nqs[qi] = -a.q_sig[(size_t)row * HD + h * DK + d] * LOG2E;
  }
  const float* kp = a.k_p + ((size_t)(b * NQ)) * HD + h * DK + d;
  const float* vp = a.v_p + ((size_t)(b * NQ)) * HD + h * DK + d;

  float acc[16];
  #pragma unroll
  for (int qi = 0; qi < 16; ++qi) acc[qi] = 0.f;

  for (int k = kbeg; k < kend; ++k) {
    const float kv = kp[(size_t)k * HD];
    const float vv = vp[(size_t)k * HD];
    #pragma unroll
    for (int qi = 0; qi < 16; ++qi) {
      const float e = fexp2(nqs[qi] * kv);          // e^(-qs*kv)
      const float g = vv * frcp(1.f + e);           // sigmoid(qs*kv)*vv
      acc[qi] += sm.S[qi][k] * g;
    }
  }
  #pragma unroll
  for (int qi = 0; qi < 16; ++qi) sm.R[kg][qi][d] = acc[qi];
  __syncthreads();

  #pragma unroll
  for (int j = 0; j < 2; ++j) {
    const int idx = t + (j << 9);
    const int qi = idx >> 6, dd = idx & 63;
    const int q = q0 + qi;
    if (q < NQ) {
      float s = 0.f;
      #pragma unroll
      for (int kk = 0; kk < 8; ++kk) s += sm.R[kk][qi][dd];
      a.image[((size_t)(b * NQ) + q) * HD + h * DK + dd] = s;
    }
  }
  __syncthreads();
}

// ---------------- phase 3: out GEMM ----------------
__device__ __forceinline__ void out_body(const FusedArgs& a, int bid, short* smem) {
  if (bid < 392) {
    const int m0 = (bid >> 3) << 4;
    const int n0 = (bid & 7) << 6;
    gemm_tile(a.image, a.Woh, a.Wol, a.bo, a.q_sig, a.outp, nullptr, nullptr,
              m0, n0, smem);
  }
}

// ---------------- single cooperative kernel ----------------
__global__ __launch_bounds__(NTHR, 4)
void fused_all(FusedArgs a) {
  __shared__ SmemU sm;
  cg::grid_group grid = cg::this_grid();
  const int bid = blockIdx.x;
  phase0_body(a, bid);
  __threadfence();
  grid.sync();
  proj_body(a, bid, sm.gemm);
  __threadfence();
  grid.sync();
  attn_body(a, bid, sm.at);
  __threadfence();
  grid.sync();
  out_body(a, bid, sm.gemm);
}

// ---------------- fallback standalone kernels (same bodies) ----------------
__global__ __launch_bounds__(NTHR, 4) void k_phase0(FusedArgs a) {
  phase0_body(a, blockIdx.x);
}
__global__ __launch_bounds__(NTHR, 4) void k_proj(FusedArgs a) {
  __shared__ SmemU sm;
  proj_body(a, blockIdx.x, sm.gemm);
}
__global__ __launch_bounds__(NTHR, 4) void k_attn(FusedArgs a) {
  __shared__ SmemU sm;
  attn_body(a, blockIdx.x, sm.at);
}
__global__ __launch_bounds__(NTHR, 4) void k_out(FusedArgs a) {
  __shared__ SmemU sm;
  out_body(a, blockIdx.x, sm.gemm);
}

extern "C" void kernel_launch(void* const* d_in, const int* in_sizes, int n_in,
                              void* d_out, int out_size, void* d_ws, size_t ws_size,
                              hipStream_t stream) {
  char* base = (char*)d_ws;
  const size_t FB = sizeof(float);
  const size_t NELF  = (size_t)MROWS * HD;   // 401408
  const size_t NELPS = (size_t)MPAD * HD;    // 425984
  const size_t WEL   = (size_t)HD * HD;      // 262144

  size_t o = 0;
  FusedArgs fa;
  fa.queries = (const float*)d_in[0];
  fa.keys    = (const float*)d_in[1];
  fa.values  = (const float*)d_in[2];
  fa.Wq = (const float*)d_in[3];  fa.bq = (const float*)d_in[4];
  fa.Wk = (const float*)d_in[5];  fa.bk = (const float*)d_in[6];
  fa.Wv = (const float*)d_in[7];  fa.bv = (const float*)d_in[8];
  fa.Wo = (const float*)d_in[9];  fa.bo = (const float*)d_in[10];
  fa.scale = (const float*)d_in[11];
  fa.q_sig = (float*)(base + o); o += NELF * FB;
  fa.k_p   = (float*)(base + o); o += NELF * FB;
  fa.v_p   = (float*)(base + o); o += NELF * FB;
  fa.image = (float*)(base + o); o += NELF * FB;
  fa.qsh = (short*)(base + o); o += NELPS * 2;
  fa.qsl = (short*)(base + o); o += NELPS * 2;
  fa.ksh = (short*)(base + o); o += NELPS * 2;
  fa.ksl = (short*)(base + o); o += NELPS * 2;
  fa.Wqh = (short*)(base + o); o += WEL * 2;
  fa.Wql = (short*)(base + o); o += WEL * 2;
  fa.Wkh = (short*)(base + o); o += WEL * 2;
  fa.Wkl = (short*)(base + o); o += WEL * 2;
  fa.Wvh = (short*)(base + o); o += WEL * 2;
  fa.Wvl = (short*)(base + o); o += WEL * 2;
  fa.Woh = (short*)(base + o); o += WEL * 2;
  fa.Wol = (short*)(base + o); o += WEL * 2;
  fa.outp = (float*)d_out;

  void* kp[] = {(void*)&fa};
  hipError_t err = hipLaunchCooperativeKernel((const void*)fused_all,
                                              dim3(GRIDB), dim3(NTHR),
                                              kp, 0, stream);
  if (err != hipSuccess) {
    // fallback: same bodies as 4 plain launches (identical outputs)
    k_phase0<<<GRIDB, NTHR, 0, stream>>>(fa);
    k_proj  <<<GRIDB, NTHR, 0, stream>>>(fa);
    k_attn  <<<GRIDB, NTHR, 0, stream>>>(fa);
    k_out   <<<GRIDB, NTHR, 0, stream>>>(fa);
  }
}

// Round 11
// 138.831 us; speedup vs baseline: 3.6043x; 3.6043x over previous
//
#include <hip/hip_runtime.h>
#include <hip/hip_bf16.h>
#include <math.h>

#define NQ 196
#define BATCH 4
#define HD 512            // H * D_K == D_MODEL
#define NH 8
#define DK 64
#define MROWS 784         // BATCH*NQ = 49*16
#define MPAD 832          // bf16 ws arrays row slack (attn tile overhang reads)

typedef __attribute__((ext_vector_type(8))) short short8;
typedef __attribute__((ext_vector_type(4))) short short4v;
typedef __attribute__((ext_vector_type(4))) float float4v;

__device__ __forceinline__ float b2f(short s) {
  return __uint_as_float(((unsigned)(unsigned short)s) << 16);
}
__device__ __forceinline__ short f2b(float x) {
  return __builtin_bit_cast(short, __float2bfloat16(x));
}
__device__ __forceinline__ float fexp2(float x) {
  float r; asm("v_exp_f32 %0, %1" : "=v"(r) : "v"(x)); return r;
}
__device__ __forceinline__ float frcp(float x) {
  float r; asm("v_rcp_f32 %0, %1" : "=v"(r) : "v"(x)); return r;
}
__device__ __forceinline__ void cvt4(float4 v, short4v& hi, short4v& lo) {
  float x[4] = {v.x, v.y, v.z, v.w};
  #pragma unroll
  for (int i = 0; i < 4; ++i) {
    hi[i] = f2b(x[i]);
    lo[i] = f2b(x[i] - b2f(hi[i]));
  }
}

// ======== k-split-2 bf16x3 MFMA GEMM, M-tile 16 (784 = 49*16, no bounds) ====
// Tile 16(M)x64(N), 512 thr = 2 k-groups x 4 waves, BK=32 per group.
// A and B both fp32 in global, cvt to bf16 hi/lo during LDS staging.
// wave w -> n-subtile w*16; per kt: 3 MFMAs. Optional gate epilogue
// (gate = q_sig reconstructed from bf16 hi/lo pair).
struct GemmArgs {
  const float* X[3]; const float* W[3]; const float* bias[3];
  float* Cf[3]; short* Ch[3]; short* Cl[3];
  const short* Gh[3]; const short* Gl[3];
};

__global__ __launch_bounds__(512)
void mgemm(GemmArgs p, int N, int K) {
  const int z = blockIdx.z;
  const float* __restrict__ X = p.X[z];
  const float* __restrict__ W = p.W[z];

  __shared__ short smem[20480];                 // 40 KB
  short* const A_ = smem;                       // [g*2+buf][hl][16*32] 512 each
  short* const B_ = smem + 4096;                // [g*2+buf][hl][64*32] 2048 each
  float* const redC = (float*)smem;             // 4KB, aliases A after barrier

  const int t = threadIdx.x;
  const int g = t >> 8;
  const int tt = t & 255;
  const int ln = t & 63, lm = ln & 15, quad = ln >> 4;
  const int w = (t >> 6) & 3;
  const int m0 = blockIdx.x * 16, n0 = blockIdx.y * 64;
  const int kb = g << 8;

  // A staging: 16 rows x 32 k fp32, 128 loader threads x float4
  const int aRow = (tt & 127) >> 3, aK = (tt & 7) << 2;
  const bool aload = tt < 128;
  const float* Ap = X + (size_t)(m0 + aRow) * K + kb + aK;
  const int aIdx = aRow * 32 + aK;
  // B staging: 64 rows x 32 k fp32, 256 threads x 8 floats (2x float4)
  const int bRow = tt >> 2, bK = (tt & 3) << 3;
  const float* Bp = W + (size_t)(n0 + bRow) * K + kb + bK;
  const int bIdx = bRow * 32 + bK;

  const int wn = w << 4;
  float4v acc = {0.f, 0.f, 0.f, 0.f};

  const int T = 8;
  float4 ra  = aload ? *(const float4*)Ap : make_float4(0.f, 0.f, 0.f, 0.f);
  float4 rb0 = *(const float4*)Bp;
  float4 rb1 = *(const float4*)(Bp + 4);
  {
    short4v bh0, bl0, bh1, bl1; cvt4(rb0, bh0, bl0); cvt4(rb1, bh1, bl1);
    short8 bh = {bh0[0],bh0[1],bh0[2],bh0[3],bh1[0],bh1[1],bh1[2],bh1[3]};
    short8 bl = {bl0[0],bl0[1],bl0[2],bl0[3],bl1[0],bl1[1],bl1[2],bl1[3]};
    *(short8*)&B_[(((g << 1) + 0) * 2 + 0) * 2048 + bIdx] = bh;
    *(short8*)&B_[(((g << 1) + 0) * 2 + 1) * 2048 + bIdx] = bl;
    if (aload) {
      short4v ahi, alo; cvt4(ra, ahi, alo);
      *(short4v*)&A_[(((g << 1) + 0) * 2 + 0) * 512 + aIdx] = ahi;
      *(short4v*)&A_[(((g << 1) + 0) * 2 + 1) * 512 + aIdx] = alo;
    }
  }

  for (int kt = 0; kt < T; ++kt) {
    const int buf = kt & 1;
    __syncthreads();                            // buf ready
    if (kt + 1 < T) {                           // register prefetch
      if (aload) ra = *(const float4*)(Ap + (size_t)(kt + 1) * 32);
      rb0 = *(const float4*)(Bp + (size_t)(kt + 1) * 32);
      rb1 = *(const float4*)(Bp + (size_t)(kt + 1) * 32 + 4);
    }
    const short* Ab = &A_[((g << 1) + buf) * 2 * 512];
    const short* Bb = &B_[((g << 1) + buf) * 2 * 2048];
    short8 fah = *(const short8*)&Ab[0 * 512 + lm * 32 + (quad << 3)];
    short8 fal = *(const short8*)&Ab[1 * 512 + lm * 32 + (quad << 3)];
    short8 fbh = *(const short8*)&Bb[0 * 2048 + (wn + lm) * 32 + (quad << 3)];
    short8 fbl = *(const short8*)&Bb[1 * 2048 + (wn + lm) * 32 + (quad << 3)];
    acc = __builtin_amdgcn_mfma_f32_16x16x32_bf16(fah, fbh, acc, 0,0,0);
    acc = __builtin_amdgcn_mfma_f32_16x16x32_bf16(fah, fbl, acc, 0,0,0);
    acc = __builtin_amdgcn_mfma_f32_16x16x32_bf16(fal, fbh, acc, 0,0,0);
    if (kt + 1 < T) {
      const int nb = buf ^ 1;
      short4v bh0, bl0, bh1, bl1; cvt4(rb0, bh0, bl0); cvt4(rb1, bh1, bl1);
      short8 bh = {bh0[0],bh0[1],bh0[2],bh0[3],bh1[0],bh1[1],bh1[2],bh1[3]};
      short8 bl = {bl0[0],bl0[1],bl0[2],bl0[3],bl1[0],bl1[1],bl1[2],bl1[3]};
      *(short8*)&B_[(((g << 1) + nb) * 2 + 0) * 2048 + bIdx] = bh;
      *(short8*)&B_[(((g << 1) + nb) * 2 + 1) * 2048 + bIdx] = bl;
      if (aload) {
        short4v ahi, alo; cvt4(ra, ahi, alo);
        *(short4v*)&A_[(((g << 1) + nb) * 2 + 0) * 512 + aIdx] = ahi;
        *(short4v*)&A_[(((g << 1) + nb) * 2 + 1) * 512 + aIdx] = alo;
      }
    }
  }

  __syncthreads();
  if (g == 1) *(float4v*)&redC[tt * 4] = acc;
  __syncthreads();
  if (g == 0) {
    const float* bias = p.bias[z];
    const short* Gh = p.Gh[z]; const short* Gl = p.Gl[z];
    float* Cf = p.Cf[z]; short* Ch = p.Ch[z]; short* Cl = p.Cl[z];
    const int n = n0 + wn + lm;
    const float bv = bias[n];
    #pragma unroll
    for (int r = 0; r < 4; ++r) {
      const int m = m0 + (quad << 2) + r;
      float c = acc[r] + redC[tt * 4 + r] + bv;
      if (Gh) {
        const size_t gi = (size_t)m * N + n;
        const float qg = b2f(Gh[gi]) + b2f(Gl[gi]);
        c = __fdividef(c, 1.f + __expf(-qg * c));   // sigmoid(qg*c)*c
      }
      if (Cf) Cf[(size_t)m * N + n] = c;
      if (Ch) {
        const short hi = f2b(c);
        Ch[(size_t)m * N + n] = hi;
        Cl[(size_t)m * N + n] = f2b(c - b2f(hi));
      }
    }
  }
}

// ======== fused attention: scores (MFMA) + softmax + gated PV, 512 thr ======
// One block per (q-tile 16, h, b); 8 waves. S and p never leave LDS.
__global__ __launch_bounds__(512)
void attn_fused(const short* __restrict__ qsh, const short* __restrict__ qsl,
                const short* __restrict__ ksh, const short* __restrict__ ksl,
                const float* __restrict__ kpg, const float* __restrict__ vpg,
                const float* __restrict__ scg, float* __restrict__ img) {
  const int q0 = blockIdx.x * 16;
  const int h  = blockIdx.y;
  const int b  = blockIdx.z;
  const int t  = threadIdx.x;
  const int w = t >> 6, ln = t & 63;
  const int lm = ln & 15, quad = ln >> 4;
  const float L2E = 1.4426950408889634f;

  __shared__ float S[16][210];     // scores, then p (broadcast reads are free)
  __shared__ float R[8][16][64];   // pv k-group partials (32 KB)

  // ---- phase 1: S = q_sig . k_p^T (bf16x3 MFMA), waves stride nt by 8 ----
  const size_t abase = ((size_t)(b * NQ) + q0 + lm) * HD + h * DK + (quad << 3);
  short8 ah0 = *(const short8*)(qsh + abase);
  short8 ah1 = *(const short8*)(qsh + abase + 32);
  short8 al0 = *(const short8*)(qsl + abase);
  short8 al1 = *(const short8*)(qsl + abase + 32);

  for (int nt = w; nt < 13; nt += 8) {
    const size_t bbase = ((size_t)(b * NQ) + nt * 16 + lm) * HD + h * DK + (quad << 3);
    short8 bh0 = *(const short8*)(ksh + bbase);
    short8 bh1 = *(const short8*)(ksh + bbase + 32);
    short8 bl0 = *(const short8*)(ksl + bbase);
    short8 bl1 = *(const short8*)(ksl + bbase + 32);
    float4v acc = {0.f, 0.f, 0.f, 0.f};
    acc = __builtin_amdgcn_mfma_f32_16x16x32_bf16(ah0, bh0, acc, 0,0,0);
    acc = __builtin_amdgcn_mfma_f32_16x16x32_bf16(ah1, bh1, acc, 0,0,0);
    acc = __builtin_amdgcn_mfma_f32_16x16x32_bf16(ah0, bl0, acc, 0,0,0);
    acc = __builtin_amdgcn_mfma_f32_16x16x32_bf16(ah1, bl1, acc, 0,0,0);
    acc = __builtin_amdgcn_mfma_f32_16x16x32_bf16(al0, bh0, acc, 0,0,0);
    acc = __builtin_amdgcn_mfma_f32_16x16x32_bf16(al1, bh1, acc, 0,0,0);
    #pragma unroll
    for (int r = 0; r < 4; ++r)
      S[(quad << 2) + r][nt * 16 + lm] = acc[r];
  }
  __syncthreads();

  // ---- phase 2: softmax in place (wave w: rows 2w, 2w+1) ----
  for (int i = 0; i < 2; ++i) {
    const int rr = (w << 1) + i;
    const int q = q0 + rr;
    const bool qok = q < NQ;
    const float* srow = scg + ((size_t)h * NQ + (qok ? q : 0)) * NQ;
    float att[4];
    #pragma unroll
    for (int j = 0; j < 4; ++j) {
      const int c = ln + (j << 6);
      att[j] = -1e30f;
      if (c < NQ) att[j] = S[rr][c] * srow[c] * L2E;
    }
    float m = fmaxf(fmaxf(att[0], att[1]), fmaxf(att[2], att[3]));
    #pragma unroll
    for (int off = 32; off; off >>= 1) m = fmaxf(m, __shfl_xor(m, off, 64));
    float e[4], s = 0.f;
    #pragma unroll
    for (int j = 0; j < 4; ++j) { e[j] = fexp2(att[j] - m); s += e[j]; }
    #pragma unroll
    for (int off = 32; off; off >>= 1) s += __shfl_xor(s, off, 64);
    const float rinv = __fdividef(1.f, s);
    #pragma unroll
    for (int j = 0; j < 4; ++j) {
      const int c = ln + (j << 6);
      if (c < NQ) S[rr][c] = e[j] * rinv;
    }
  }
  __syncthreads();

  // ---- phase 3: gated PV. thread = (d = ln, kgroup = w of 8). ----
  const int d = ln;
  const int kg = w;
  const int kbeg = (kg * 49) >> 1;              // 196 split into 8 ranges
  const int kend = ((kg + 1) * 49) >> 1;
  const float LOG2E = 1.4426950408889634f;

  float nqs[16];
  #pragma unroll
  for (int qi = 0; qi < 16; ++qi) {
    const int row = min(b * NQ + q0 + qi, MROWS - 1);   // clamp tile overhang
    const size_t gi = (size_t)row * HD + h * DK + d;
    nqs[qi] = -(b2f(qsh[gi]) + b2f(qsl[gi])) * LOG2E;
  }
  const float* kp = kpg + ((size_t)(b * NQ)) * HD + h * DK + d;
  const float* vp = vpg + ((size_t)(b * NQ)) * HD + h * DK + d;

  float acc[16];
  #pragma unroll
  for (int qi = 0; qi < 16; ++qi) acc[qi] = 0.f;

  for (int k = kbeg; k < kend; ++k) {
    const float kv = kp[(size_t)k * HD];
    const float vv = vp[(size_t)k * HD];
    #pragma unroll
    for (int qi = 0; qi < 16; ++qi) {
      const float e = fexp2(nqs[qi] * kv);          // e^(-qs*kv)
      const float g = vv * frcp(1.f + e);           // sigmoid(qs*kv)*vv
      acc[qi] += S[qi][k] * g;
    }
  }
  #pragma unroll
  for (int qi = 0; qi < 16; ++qi) R[kg][qi][d] = acc[qi];
  __syncthreads();

  #pragma unroll
  for (int j = 0; j < 2; ++j) {
    const int idx = t + (j << 9);
    const int qi = idx >> 6, dd = idx & 63;
    const int q = q0 + qi;
    if (q < NQ) {
      float s = 0.f;
      #pragma unroll
      for (int kk = 0; kk < 8; ++kk) s += R[kk][qi][dd];
      img[((size_t)(b * NQ) + q) * HD + h * DK + dd] = s;
    }
  }
}

extern "C" void kernel_launch(void* const* d_in, const int* in_sizes, int n_in,
                              void* d_out, int out_size, void* d_ws, size_t ws_size,
                              hipStream_t stream) {
  const float* queries = (const float*)d_in[0];
  const float* keys    = (const float*)d_in[1];
  const float* values  = (const float*)d_in[2];
  const float* Wq = (const float*)d_in[3];
  const float* bq = (const float*)d_in[4];
  const float* Wk = (const float*)d_in[5];
  const float* bk = (const float*)d_in[6];
  const float* Wv = (const float*)d_in[7];
  const float* bv = (const float*)d_in[8];
  const float* Wo = (const float*)d_in[9];
  const float* bo = (const float*)d_in[10];
  const float* scale = (const float*)d_in[11];

  char* base = (char*)d_ws;
  const size_t FB = sizeof(float);
  const size_t NELF  = (size_t)MROWS * HD;   // 401408
  const size_t NELPS = (size_t)MPAD * HD;    // 425984

  size_t o = 0;
  float* k_p   = (float*)(base + o); o += NELF * FB;
  float* v_p   = (float*)(base + o); o += NELF * FB;
  float* image = (float*)(base + o); o += NELF * FB;
  short* qsh = (short*)(base + o); o += NELPS * 2;
  short* qsl = (short*)(base + o); o += NELPS * 2;
  short* ksh = (short*)(base + o); o += NELPS * 2;
  short* ksl = (short*)(base + o); o += NELPS * 2;

  // 1) projections: z0 q_sig (split only), z1 k_p (fp32 + split), z2 v_p (fp32)
  GemmArgs gp;
  gp.X[0] = queries; gp.W[0] = Wq; gp.bias[0] = bq;
  gp.Cf[0] = nullptr; gp.Ch[0] = qsh; gp.Cl[0] = qsl; gp.Gh[0] = nullptr; gp.Gl[0] = nullptr;
  gp.X[1] = keys;    gp.W[1] = Wk; gp.bias[1] = bk;
  gp.Cf[1] = k_p;    gp.Ch[1] = ksh; gp.Cl[1] = ksl; gp.Gh[1] = nullptr; gp.Gl[1] = nullptr;
  gp.X[2] = values;  gp.W[2] = Wv; gp.bias[2] = bv;
  gp.Cf[2] = v_p;    gp.Ch[2] = nullptr; gp.Cl[2] = nullptr; gp.Gh[2] = nullptr; gp.Gl[2] = nullptr;
  mgemm<<<dim3(MROWS/16, HD/64, 3), 512, 0, stream>>>(gp, HD, HD);

  // 2) fused scores + softmax + gated PV -> image
  attn_fused<<<dim3(13, NH, BATCH), 512, 0, stream>>>(
      qsh, qsl, ksh, ksl, k_p, v_p, scale, image);

  // 3) out = image @ Wo^T + bo, gated by q_sig (reconstructed hi+lo)
  GemmArgs go;
  go.X[0] = image; go.W[0] = Wo; go.bias[0] = bo;
  go.Cf[0] = (float*)d_out; go.Ch[0] = nullptr; go.Cl[0] = nullptr;
  go.Gh[0] = qsh; go.Gl[0] = qsl;
  for (int i = 1; i < 3; ++i) {
    go.X[i] = nullptr; go.W[i] = nullptr; go.bias[i] = nullptr;
    go.Cf[i] = nullptr; go.Ch[i] = nullptr; go.Cl[i] = nullptr;
    go.Gh[i] = nullptr; go.Gl[i] = nullptr;
  }
  mgemm<<<dim3(MROWS/16, HD/64, 1), 512, 0, stream>>>(go, HD, HD);
}